// Round 7
// baseline (312.902 us; speedup 1.0000x reference)
//
#include <hip/hip_runtime.h>
#include <hip/hip_bf16.h>
#include <math.h>

#define Hdim 1024
#define Bdim 32
#define Ldim 2048
#define Mtot (Bdim*Ldim)   // 65536

typedef __attribute__((ext_vector_type(8))) short short8v;
typedef __attribute__((ext_vector_type(4))) short short4v;
typedef __attribute__((ext_vector_type(4))) float floatx4;

static __device__ inline short f2bf(float f) {
    union { float f; unsigned u; } x; x.f = f;
    unsigned r = x.u + 0x7FFF + ((x.u >> 16) & 1);   // RNE
    return (short)(r >> 16);
}
static __device__ inline float bf2f(short s) {
    union { unsigned u; float f; } x; x.u = ((unsigned)(unsigned short)s) << 16;
    return x.f;
}

static __device__ inline float fast_tanh(float x) {
    float t = 2.0f * x;
    t = fminf(fmaxf(t, -30.0f), 30.0f);
    float e = __expf(t);
    return (e - 1.0f) / (e + 1.0f);
}

typedef __attribute__((address_space(1))) const void GVT;
typedef __attribute__((address_space(3))) void LVT;
static __device__ inline void gload_lds16(const void* g, void* l) {
    __builtin_amdgcn_global_load_lds((GVT*)g, (LVT*)l, 16, 0, 0);
}

// ---------------- Kernel 0a: enc f32 -> bf16 ----------------
__global__ __launch_bounds__(256) void convert_enc_kernel(
    const float* __restrict__ enc, short* __restrict__ enc_bf)
{
    size_t i = ((size_t)blockIdx.x * 256 + threadIdx.x) * 8;
    float4 a = *(const float4*)(enc + i);
    float4 b = *(const float4*)(enc + i + 4);
    short8v o;
    o[0]=f2bf(a.x); o[1]=f2bf(a.y); o[2]=f2bf(a.z); o[3]=f2bf(a.w);
    o[4]=f2bf(b.x); o[5]=f2bf(b.y); o[6]=f2bf(b.z); o[7]=f2bf(b.w);
    *(short8v*)(enc_bf + i) = o;
}

// ---------------- Kernel 0b: W_e f32 -> compact bf16 [1024][1024] ----------------
__global__ __launch_bounds__(256) void convert_w_kernel(
    const float* __restrict__ attn_w, short* __restrict__ w_bf)
{
    int t = blockIdx.x * 256 + threadIdx.x;
    int o = t >> 7;
    int c = t & 127;
    const float* src = attn_w + (size_t)o * 2 * Hdim + Hdim + c * 8;
    float4 a = *(const float4*)(src);
    float4 b = *(const float4*)(src + 4);
    short8v v;
    v[0]=f2bf(a.x); v[1]=f2bf(a.y); v[2]=f2bf(a.z); v[3]=f2bf(a.w);
    v[4]=f2bf(b.x); v[5]=f2bf(b.y); v[6]=f2bf(b.z); v[7]=f2bf(b.w);
    *(short8v*)(w_bf + (size_t)o * Hdim + c * 8) = v;
}

// ---------------- Kernel 1: q[b][o] = hidden[b]·W_h[o] + bias[o] ----------------
__global__ __launch_bounds__(256) void qproj_kernel(
    const float* __restrict__ hidden, const float* __restrict__ attn_w,
    const float* __restrict__ attn_b, float* __restrict__ qbuf)
{
    int w = blockIdx.x * 4 + (threadIdx.x >> 6);
    int lane = threadIdx.x & 63;
    int o = w >> 5;
    int b = w & 31;
    const float* hrow = hidden + b * Hdim;
    const float* wrow = attn_w + (size_t)o * 2 * Hdim;
    float s = 0.f;
    #pragma unroll
    for (int i = 0; i < 16; i++) s += hrow[lane + i*64] * wrow[lane + i*64];
    s += __shfl_xor(s, 1);  s += __shfl_xor(s, 2);  s += __shfl_xor(s, 4);
    s += __shfl_xor(s, 8);  s += __shfl_xor(s, 16); s += __shfl_xor(s, 32);
    if (lane == 0) qbuf[b * Hdim + o] = s + attn_b[o];
}

// ---------------- Kernel 2: 8-phase 256^2 bf16 GEMM + tanh + v-dot ----------------
// proj[m][o] = sum_k enc[m][k]*W_e[o][k]; spart[nblk][m] = sum_{o in nblk} tanh(proj+q)*v
// Structure: 8 waves (2M x 4N), BK=64, 16 K-tiles x 4 phases, dbuf LDS (128KB),
// pre-swizzled global src (chunk ^= row&7) + swizzled ds_read, counted vmcnt(2),
// setprio around MFMA quadrants.
#define NKT 16

__global__ __launch_bounds__(512, 1) void scores_kernel(
    const short* __restrict__ enc_bf,   // [Mtot][1024] bf16
    const short* __restrict__ w_bf,     // [1024][1024] bf16
    const float* __restrict__ qbuf,     // [B][H]
    const float* __restrict__ vvec,     // [H]
    float* __restrict__ spart)          // [4][Mtot]
{
    __shared__ short As[2][256*64];     // 64 KB
    __shared__ short Bs[2][256*64];     // 64 KB
    __shared__ float sred[256][4];      //  4 KB

    // XCD swizzle: grid 1024 = 8 XCD x (4 nblk x 32 mtile); nblk fastest
    int hw  = blockIdx.x;
    int xcd = hw & 7;
    int i7  = hw >> 3;                  // 0..127
    int nblk  = i7 & 3;
    int mtile = xcd * 32 + (i7 >> 2);   // 0..255
    int m0 = mtile * 256;
    int n0 = nblk * 256;

    int tid = threadIdx.x;
    int w   = tid >> 6;                 // 0..7
    int l   = tid & 63;
    int wr  = w >> 2;                   // 0..1 (M)
    int wc  = w & 3;                    // 0..3 (N)
    int r15 = l & 15;
    int kc  = l >> 4;                   // 0..3
    int rg  = l >> 4;

    // per-lane pre-swizzled global offset for staging (shorts):
    // lane l -> row (l>>3), holds global chunk (l&7)^(l>>3) at LDS chunk (l&7)
    const int glsw = (l >> 3) * Hdim + (((l & 7) ^ (l >> 3)) * 8);

#define STAGE_A(h, bb, k0) do { \
    const short* _g = enc_bf + (size_t)(m0 + (h)*128 + w*16) * Hdim + (k0) + glsw; \
    gload_lds16(_g,            &As[bb][(h)*8192 + w*1024]);        \
    gload_lds16(_g + 8*Hdim,   &As[bb][(h)*8192 + w*1024 + 512]);  \
} while (0)
#define STAGE_B(h, bb, k0) do { \
    const short* _g = w_bf + (size_t)(n0 + (h)*128 + w*16) * Hdim + (k0) + glsw; \
    gload_lds16(_g,            &Bs[bb][(h)*8192 + w*1024]);        \
    gload_lds16(_g + 8*Hdim,   &Bs[bb][(h)*8192 + w*1024 + 512]);  \
} while (0)
    // swizzled fragment reads (chunk = (kk*4+kc) ^ (row&7), row&7 == l&7)
#define LDA(mi, kk) (*(const short8v*)(&As[cur][(wr*128 + (mi)*16 + r15)*64 + ((((kk)*4 + kc) ^ (l & 7)) * 8)]))
#define LDB(ni, kk) (*(const short8v*)(&Bs[cur][(wc*64  + (ni)*16 + r15)*64 + ((((kk)*4 + kc) ^ (l & 7)) * 8)]))

    floatx4 acc[8][4];
    #pragma unroll
    for (int i = 0; i < 8; i++)
        #pragma unroll
        for (int j = 0; j < 4; j++) acc[i][j] = (floatx4){0.f, 0.f, 0.f, 0.f};

    short8v af[4][2], bf[4][2];

    // prologue: stage K-tile 0 into buffer 0 (8 loads/thread)
    STAGE_A(0, 0, 0); STAGE_A(1, 0, 0);
    STAGE_B(0, 0, 0); STAGE_B(1, 0, 0);

    for (int kt = 0; kt < NKT; kt++) {
        int cur = kt & 1;
        int nxt = cur ^ 1;
        int kn  = (kt + 1) * 64;

        // ---- Phase 1: stage A-half0(t+1); counted vmcnt; reads mi0-3 + ni0-1; MFMA Q(0,0) ----
        if (kt < NKT - 1) {
            STAGE_A(0, nxt, kn);
            asm volatile("s_waitcnt vmcnt(2)" ::: "memory");
        } else {
            asm volatile("s_waitcnt vmcnt(0)" ::: "memory");
        }
        __builtin_amdgcn_s_barrier();
        #pragma unroll
        for (int mi = 0; mi < 4; mi++)
            #pragma unroll
            for (int kk = 0; kk < 2; kk++) af[mi][kk] = LDA(mi, kk);
        #pragma unroll
        for (int ni = 0; ni < 2; ni++)
            #pragma unroll
            for (int kk = 0; kk < 2; kk++) bf[ni][kk] = LDB(ni, kk);
        __builtin_amdgcn_s_setprio(1);
        #pragma unroll
        for (int mi = 0; mi < 4; mi++)
            #pragma unroll
            for (int ni = 0; ni < 2; ni++)
                #pragma unroll
                for (int kk = 0; kk < 2; kk++)
                    acc[mi][ni] = __builtin_amdgcn_mfma_f32_16x16x32_bf16(af[mi][kk], bf[ni][kk], acc[mi][ni], 0, 0, 0);
        __builtin_amdgcn_s_setprio(0);
        __builtin_amdgcn_s_barrier();

        // ---- Phase 2: reads ni2-3; stage A-half1; MFMA Q(0,2) ----
        #pragma unroll
        for (int ni = 2; ni < 4; ni++)
            #pragma unroll
            for (int kk = 0; kk < 2; kk++) bf[ni][kk] = LDB(ni, kk);
        if (kt < NKT - 1) STAGE_A(1, nxt, kn);
        __builtin_amdgcn_s_barrier();
        __builtin_amdgcn_s_setprio(1);
        #pragma unroll
        for (int mi = 0; mi < 4; mi++)
            #pragma unroll
            for (int ni = 2; ni < 4; ni++)
                #pragma unroll
                for (int kk = 0; kk < 2; kk++)
                    acc[mi][ni] = __builtin_amdgcn_mfma_f32_16x16x32_bf16(af[mi][kk], bf[ni][kk], acc[mi][ni], 0, 0, 0);
        __builtin_amdgcn_s_setprio(0);
        __builtin_amdgcn_s_barrier();

        // ---- Phase 3: reads mi4-7 (reuse af regs); stage B-half0; MFMA Q(4,0) ----
        #pragma unroll
        for (int mi = 0; mi < 4; mi++)
            #pragma unroll
            for (int kk = 0; kk < 2; kk++) af[mi][kk] = LDA(mi + 4, kk);
        if (kt < NKT - 1) STAGE_B(0, nxt, kn);
        __builtin_amdgcn_s_barrier();
        __builtin_amdgcn_s_setprio(1);
        #pragma unroll
        for (int mi = 0; mi < 4; mi++)
            #pragma unroll
            for (int ni = 0; ni < 2; ni++)
                #pragma unroll
                for (int kk = 0; kk < 2; kk++)
                    acc[mi + 4][ni] = __builtin_amdgcn_mfma_f32_16x16x32_bf16(af[mi][kk], bf[ni][kk], acc[mi + 4][ni], 0, 0, 0);
        __builtin_amdgcn_s_setprio(0);
        __builtin_amdgcn_s_barrier();

        // ---- Phase 4: stage B-half1; MFMA Q(4,2) ----
        if (kt < NKT - 1) STAGE_B(1, nxt, kn);
        __builtin_amdgcn_s_barrier();
        __builtin_amdgcn_s_setprio(1);
        #pragma unroll
        for (int mi = 0; mi < 4; mi++)
            #pragma unroll
            for (int ni = 2; ni < 4; ni++)
                #pragma unroll
                for (int kk = 0; kk < 2; kk++)
                    acc[mi + 4][ni] = __builtin_amdgcn_mfma_f32_16x16x32_bf16(af[mi][kk], bf[ni][kk], acc[mi + 4][ni], 0, 0, 0);
        __builtin_amdgcn_s_setprio(0);
        __builtin_amdgcn_s_barrier();
    }

    // ---- epilogue: tanh(proj + q) * v, reduce over the block's 256 cols ----
    #pragma unroll
    for (int mi = 0; mi < 8; mi++) {
        float rs[4] = {0.f, 0.f, 0.f, 0.f};
        #pragma unroll
        for (int ni = 0; ni < 4; ni++) {
            int o = n0 + wc*64 + ni*16 + r15;
            float vo = vvec[o];
            #pragma unroll
            for (int reg = 0; reg < 4; reg++) {
                int r = wr*128 + mi*16 + rg*4 + reg;   // tile row; b = r&31 (m0 % 32 == 0)
                float p = acc[mi][ni][reg] + qbuf[(r & 31) * Hdim + o];
                rs[reg] += fast_tanh(p) * vo;
            }
        }
        #pragma unroll
        for (int reg = 0; reg < 4; reg++) {
            float s = rs[reg];
            s += __shfl_xor(s, 1); s += __shfl_xor(s, 2);
            s += __shfl_xor(s, 4); s += __shfl_xor(s, 8);
            if (r15 == 0) {
                int r = wr*128 + mi*16 + rg*4 + reg;
                sred[r][wc] = s;
            }
        }
    }
    __syncthreads();
    if (tid < 256)
        spart[(size_t)nblk * Mtot + m0 + tid] = sred[tid][0] + sred[tid][1] + sred[tid][2] + sred[tid][3];
#undef STAGE_A
#undef STAGE_B
#undef LDA
#undef LDB
}

// ---------------- Kernel 3: reduce 4 partials + softmax over L (per b) ----------------
__global__ __launch_bounds__(256) void softmax_kernel(
    const float* __restrict__ spart,   // [4][Mtot], m = l*32+b
    float* __restrict__ attn)          // [B][L]
{
    int b = blockIdx.x;
    int t = threadIdx.x;
    __shared__ float rmax[4], rsum[4];
    float sv[8];
    float mx = -1e30f;
    #pragma unroll
    for (int i = 0; i < 8; i++) {
        int l = t + i * 256;
        int m = l * Bdim + b;
        float s = 0.f;
        #pragma unroll
        for (int p = 0; p < 4; p++) s += spart[(size_t)p * Mtot + m];
        sv[i] = s;
        mx = fmaxf(mx, s);
    }
    #pragma unroll
    for (int off = 1; off < 64; off <<= 1) mx = fmaxf(mx, __shfl_xor(mx, off));
    if ((t & 63) == 0) rmax[t >> 6] = mx;
    __syncthreads();
    mx = fmaxf(fmaxf(rmax[0], rmax[1]), fmaxf(rmax[2], rmax[3]));
    float sum = 0.f;
    #pragma unroll
    for (int i = 0; i < 8; i++) { sv[i] = __expf(sv[i] - mx); sum += sv[i]; }
    #pragma unroll
    for (int off = 1; off < 64; off <<= 1) sum += __shfl_xor(sum, off);
    if ((t & 63) == 0) rsum[t >> 6] = sum;
    __syncthreads();
    sum = rsum[0] + rsum[1] + rsum[2] + rsum[3];
    float inv = 1.f / sum;
    #pragma unroll
    for (int i = 0; i < 8; i++)
        attn[(size_t)b * Ldim + t + i * 256] = sv[i] * inv;
}

// ---------------- Kernel 4: context partials over L-chunks (bf16 enc) ----------------
__global__ __launch_bounds__(256) void context_part_kernel(
    const short* __restrict__ enc_bf,
    const float* __restrict__ attn,
    float* __restrict__ cpart)         // [64][B][H]
{
    int b = blockIdx.x & 31;
    int c = blockIdx.x >> 5;
    int t = threadIdx.x;
    float a0 = 0.f, a1 = 0.f, a2 = 0.f, a3 = 0.f;
    int l0 = c * 32;
    for (int i = 0; i < 32; i++) {
        int l = l0 + i;
        float a = attn[(size_t)b * Ldim + l];
        short4v e = *(const short4v*)(enc_bf + (size_t)(l * Bdim + b) * Hdim + t * 4);
        a0 += a * bf2f(e.x); a1 += a * bf2f(e.y);
        a2 += a * bf2f(e.z); a3 += a * bf2f(e.w);
    }
    float4 r; r.x = a0; r.y = a1; r.z = a2; r.w = a3;
    *(float4*)(cpart + ((size_t)c * Bdim + b) * Hdim + t * 4) = r;
}

// ---------------- Kernel 5: reduce context partials ----------------
__global__ __launch_bounds__(256) void context_reduce_kernel(
    const float* __restrict__ cpart, float* __restrict__ out)
{
    int idx = blockIdx.x * 256 + threadIdx.x;
    float s = 0.f;
    for (int c = 0; c < 64; c++) s += cpart[(size_t)c * (Bdim * Hdim) + idx];
    out[idx] = s;
}

extern "C" void kernel_launch(void* const* d_in, const int* in_sizes, int n_in,
                              void* d_out, int out_size, void* d_ws, size_t ws_size,
                              hipStream_t stream)
{
    const float* hidden = (const float*)d_in[0];
    const float* enc    = (const float*)d_in[1];   // (L,B,H), m = l*32+b
    const float* attn_w = (const float*)d_in[2];
    const float* attn_b = (const float*)d_in[3];
    const float* vvec   = (const float*)d_in[4];
    float* out = (float*)d_out;

    char* ws = (char*)d_ws;
    size_t off = 0;
    short* enc_bf = (short*)(ws + off); off += (size_t)Mtot * Hdim * 2;       // 134.2 MB
    short* w_bf   = (short*)(ws + off); off += (size_t)Hdim * Hdim * 2;       //   2.1 MB
    float* qbuf   = (float*)(ws + off); off += (size_t)Bdim * Hdim * 4;       //   0.13 MB
    float* spart  = (float*)(ws + off); off += (size_t)4 * Mtot * 4;          //   1.0 MB
    float* attnp  = (float*)(ws + off); off += (size_t)Mtot * 4;              //   0.26 MB
    float* cpart  = (float*)(ws + off);                                       //   8.4 MB

    convert_enc_kernel<<<32768, 256, 0, stream>>>(enc, enc_bf);
    convert_w_kernel<<<512, 256, 0, stream>>>(attn_w, w_bf);
    qproj_kernel<<<8192, 256, 0, stream>>>(hidden, attn_w, attn_b, qbuf);
    scores_kernel<<<1024, 512, 0, stream>>>(enc_bf, w_bf, qbuf, vvec, spart);
    softmax_kernel<<<Bdim, 256, 0, stream>>>(spart, attnp);
    context_part_kernel<<<2048, 256, 0, stream>>>(enc_bf, attnp, cpart);
    context_reduce_kernel<<<128, 256, 0, stream>>>(cpart, out);
}

// Round 8
// 285.306 us; speedup vs baseline: 1.0967x; 1.0967x over previous
//
#include <hip/hip_runtime.h>
#include <hip/hip_bf16.h>
#include <math.h>

#define Hdim 1024
#define Bdim 32
#define Ldim 2048
#define Mtot (Bdim*Ldim)   // 65536

typedef __attribute__((ext_vector_type(8))) short short8v;
typedef __attribute__((ext_vector_type(4))) short short4v;
typedef __attribute__((ext_vector_type(4))) float floatx4;

static __device__ inline short f2bf(float f) {
    union { float f; unsigned u; } x; x.f = f;
    unsigned r = x.u + 0x7FFF + ((x.u >> 16) & 1);   // RNE
    return (short)(r >> 16);
}
static __device__ inline float bf2f(short s) {
    union { unsigned u; float f; } x; x.u = ((unsigned)(unsigned short)s) << 16;
    return x.f;
}

static __device__ inline float fast_tanh(float x) {
    float t = 2.0f * x;
    t = fminf(fmaxf(t, -30.0f), 30.0f);
    float e = __expf(t);
    return (e - 1.0f) / (e + 1.0f);
}

typedef __attribute__((address_space(1))) const void GVT;
typedef __attribute__((address_space(3))) void LVT;
static __device__ inline void gload_lds16(const void* g, void* l) {
    __builtin_amdgcn_global_load_lds((GVT*)g, (LVT*)l, 16, 0, 0);
}

// ---------------- Kernel 0a: enc f32 -> bf16 ----------------
__global__ __launch_bounds__(256) void convert_enc_kernel(
    const float* __restrict__ enc, short* __restrict__ enc_bf)
{
    size_t i = ((size_t)blockIdx.x * 256 + threadIdx.x) * 8;
    float4 a = *(const float4*)(enc + i);
    float4 b = *(const float4*)(enc + i + 4);
    short8v o;
    o[0]=f2bf(a.x); o[1]=f2bf(a.y); o[2]=f2bf(a.z); o[3]=f2bf(a.w);
    o[4]=f2bf(b.x); o[5]=f2bf(b.y); o[6]=f2bf(b.z); o[7]=f2bf(b.w);
    *(short8v*)(enc_bf + i) = o;
}

// ---------------- Kernel 0b: W_e f32 -> compact bf16 [1024][1024] ----------------
__global__ __launch_bounds__(256) void convert_w_kernel(
    const float* __restrict__ attn_w, short* __restrict__ w_bf)
{
    int t = blockIdx.x * 256 + threadIdx.x;
    int o = t >> 7;
    int c = t & 127;
    const float* src = attn_w + (size_t)o * 2 * Hdim + Hdim + c * 8;
    float4 a = *(const float4*)(src);
    float4 b = *(const float4*)(src + 4);
    short8v v;
    v[0]=f2bf(a.x); v[1]=f2bf(a.y); v[2]=f2bf(a.z); v[3]=f2bf(a.w);
    v[4]=f2bf(b.x); v[5]=f2bf(b.y); v[6]=f2bf(b.z); v[7]=f2bf(b.w);
    *(short8v*)(w_bf + (size_t)o * Hdim + c * 8) = v;
}

// ---------------- Kernel 1: q[b][o] = hidden[b]·W_h[o] + bias[o] ----------------
__global__ __launch_bounds__(256) void qproj_kernel(
    const float* __restrict__ hidden, const float* __restrict__ attn_w,
    const float* __restrict__ attn_b, float* __restrict__ qbuf)
{
    int w = blockIdx.x * 4 + (threadIdx.x >> 6);
    int lane = threadIdx.x & 63;
    int o = w >> 5;
    int b = w & 31;
    const float* hrow = hidden + b * Hdim;
    const float* wrow = attn_w + (size_t)o * 2 * Hdim;
    float s = 0.f;
    #pragma unroll
    for (int i = 0; i < 16; i++) s += hrow[lane + i*64] * wrow[lane + i*64];
    s += __shfl_xor(s, 1);  s += __shfl_xor(s, 2);  s += __shfl_xor(s, 4);
    s += __shfl_xor(s, 8);  s += __shfl_xor(s, 16); s += __shfl_xor(s, 32);
    if (lane == 0) qbuf[b * Hdim + o] = s + attn_b[o];
}

// ---------------- Kernel 2: 8-phase 256^2 bf16 GEMM + tanh + v-dot ----------------
// Fixes vs r7: (1) all 8 stage-loads of tile kt+1 front-loaded into phases 1-2
// (cover >= 2.5 phases); (2) ds_reads issued BEFORE barrier (latency hidden
// under barrier wait); (3) single vmcnt(0) drain per K-tile at phase 4 (loads
// have had ~2.5 phases; queue holds only tile kt+1); (4) prologue drain added.
#define NKT 16

__global__ __launch_bounds__(512, 1) void scores_kernel(
    const short* __restrict__ enc_bf,   // [Mtot][1024] bf16
    const short* __restrict__ w_bf,     // [1024][1024] bf16
    const float* __restrict__ qbuf,     // [B][H]
    const float* __restrict__ vvec,     // [H]
    float* __restrict__ spart)          // [4][Mtot]
{
    __shared__ short As[2][256*64];     // 64 KB
    __shared__ short Bs[2][256*64];     // 64 KB
    __shared__ float sred[256][4];      //  4 KB

    // XCD swizzle: grid 1024 = 8 XCD x (4 nblk x 32 mtile); nblk fastest
    int hw  = blockIdx.x;
    int xcd = hw & 7;
    int i7  = hw >> 3;                  // 0..127
    int nblk  = i7 & 3;
    int mtile = xcd * 32 + (i7 >> 2);   // 0..255
    int m0 = mtile * 256;
    int n0 = nblk * 256;

    int tid = threadIdx.x;
    int w   = tid >> 6;                 // 0..7
    int l   = tid & 63;
    int wr  = w >> 2;                   // 0..1 (M)
    int wc  = w & 3;                    // 0..3 (N)
    int r15 = l & 15;
    int kc  = l >> 4;                   // 0..3
    int rg  = l >> 4;

    // per-lane pre-swizzled global offset for staging (shorts):
    // lane l -> row (l>>3), holds global chunk (l&7)^(l>>3) at LDS chunk (l&7)
    const int glsw = (l >> 3) * Hdim + (((l & 7) ^ (l >> 3)) * 8);

#define STAGE_A(h, bb, k0) do { \
    const short* _g = enc_bf + (size_t)(m0 + (h)*128 + w*16) * Hdim + (k0) + glsw; \
    gload_lds16(_g,            &As[bb][(h)*8192 + w*1024]);        \
    gload_lds16(_g + 8*Hdim,   &As[bb][(h)*8192 + w*1024 + 512]);  \
} while (0)
#define STAGE_B(h, bb, k0) do { \
    const short* _g = w_bf + (size_t)(n0 + (h)*128 + w*16) * Hdim + (k0) + glsw; \
    gload_lds16(_g,            &Bs[bb][(h)*8192 + w*1024]);        \
    gload_lds16(_g + 8*Hdim,   &Bs[bb][(h)*8192 + w*1024 + 512]);  \
} while (0)
    // swizzled fragment reads (chunk = (kk*4+kc) ^ (row&7), row&7 == l&7)
#define LDA(mi, kk) (*(const short8v*)(&As[cur][(wr*128 + (mi)*16 + r15)*64 + ((((kk)*4 + kc) ^ (l & 7)) * 8)]))
#define LDB(ni, kk) (*(const short8v*)(&Bs[cur][(wc*64  + (ni)*16 + r15)*64 + ((((kk)*4 + kc) ^ (l & 7)) * 8)]))

    floatx4 acc[8][4];
    #pragma unroll
    for (int i = 0; i < 8; i++)
        #pragma unroll
        for (int j = 0; j < 4; j++) acc[i][j] = (floatx4){0.f, 0.f, 0.f, 0.f};

    short8v af[4][2], bf[4][2];

    // prologue: stage K-tile 0 into buffer 0, drain fully
    STAGE_A(0, 0, 0); STAGE_A(1, 0, 0);
    STAGE_B(0, 0, 0); STAGE_B(1, 0, 0);
    asm volatile("s_waitcnt vmcnt(0)" ::: "memory");
    __syncthreads();

    for (int kt = 0; kt < NKT; kt++) {
        int cur = kt & 1;
        int nxt = cur ^ 1;
        int kn  = (kt + 1) * 64;
        bool pf = (kt < NKT - 1);

        // ---- Phase 1: ds_read af(mi0-3)+bf(ni0-1); stage A(t+1) both halves; MFMA Q(0..3,0..1) ----
        #pragma unroll
        for (int mi = 0; mi < 4; mi++)
            #pragma unroll
            for (int kk = 0; kk < 2; kk++) af[mi][kk] = LDA(mi, kk);
        #pragma unroll
        for (int ni = 0; ni < 2; ni++)
            #pragma unroll
            for (int kk = 0; kk < 2; kk++) bf[ni][kk] = LDB(ni, kk);
        if (pf) { STAGE_A(0, nxt, kn); STAGE_A(1, nxt, kn); }
        __builtin_amdgcn_s_barrier();
        __builtin_amdgcn_s_setprio(1);
        #pragma unroll
        for (int mi = 0; mi < 4; mi++)
            #pragma unroll
            for (int ni = 0; ni < 2; ni++)
                #pragma unroll
                for (int kk = 0; kk < 2; kk++)
                    acc[mi][ni] = __builtin_amdgcn_mfma_f32_16x16x32_bf16(af[mi][kk], bf[ni][kk], acc[mi][ni], 0, 0, 0);
        __builtin_amdgcn_s_setprio(0);
        __builtin_amdgcn_s_barrier();

        // ---- Phase 2: ds_read bf(ni2-3); stage B(t+1) both halves; MFMA Q(0..3,2..3) ----
        #pragma unroll
        for (int ni = 2; ni < 4; ni++)
            #pragma unroll
            for (int kk = 0; kk < 2; kk++) bf[ni][kk] = LDB(ni, kk);
        if (pf) { STAGE_B(0, nxt, kn); STAGE_B(1, nxt, kn); }
        __builtin_amdgcn_s_barrier();
        __builtin_amdgcn_s_setprio(1);
        #pragma unroll
        for (int mi = 0; mi < 4; mi++)
            #pragma unroll
            for (int ni = 2; ni < 4; ni++)
                #pragma unroll
                for (int kk = 0; kk < 2; kk++)
                    acc[mi][ni] = __builtin_amdgcn_mfma_f32_16x16x32_bf16(af[mi][kk], bf[ni][kk], acc[mi][ni], 0, 0, 0);
        __builtin_amdgcn_s_setprio(0);
        __builtin_amdgcn_s_barrier();

        // ---- Phase 3: ds_read af(mi4-7, reuse regs); MFMA Q(4..7,0..1) ----
        #pragma unroll
        for (int mi = 0; mi < 4; mi++)
            #pragma unroll
            for (int kk = 0; kk < 2; kk++) af[mi][kk] = LDA(mi + 4, kk);
        __builtin_amdgcn_s_barrier();
        __builtin_amdgcn_s_setprio(1);
        #pragma unroll
        for (int mi = 0; mi < 4; mi++)
            #pragma unroll
            for (int ni = 0; ni < 2; ni++)
                #pragma unroll
                for (int kk = 0; kk < 2; kk++)
                    acc[mi + 4][ni] = __builtin_amdgcn_mfma_f32_16x16x32_bf16(af[mi][kk], bf[ni][kk], acc[mi + 4][ni], 0, 0, 0);
        __builtin_amdgcn_s_setprio(0);
        __builtin_amdgcn_s_barrier();

        // ---- Phase 4: drain tile t+1 loads (issued ~2.5 phases ago); MFMA Q(4..7,2..3) ----
        if (pf) asm volatile("s_waitcnt vmcnt(0)" ::: "memory");
        __builtin_amdgcn_s_barrier();
        __builtin_amdgcn_s_setprio(1);
        #pragma unroll
        for (int mi = 0; mi < 4; mi++)
            #pragma unroll
            for (int ni = 2; ni < 4; ni++)
                #pragma unroll
                for (int kk = 0; kk < 2; kk++)
                    acc[mi + 4][ni] = __builtin_amdgcn_mfma_f32_16x16x32_bf16(af[mi][kk], bf[ni][kk], acc[mi + 4][ni], 0, 0, 0);
        __builtin_amdgcn_s_setprio(0);
        __builtin_amdgcn_s_barrier();
    }

    // ---- epilogue: tanh(proj + q) * v, reduce over the block's 256 cols ----
    #pragma unroll
    for (int mi = 0; mi < 8; mi++) {
        float rs[4] = {0.f, 0.f, 0.f, 0.f};
        #pragma unroll
        for (int ni = 0; ni < 4; ni++) {
            int o = n0 + wc*64 + ni*16 + r15;
            float vo = vvec[o];
            #pragma unroll
            for (int reg = 0; reg < 4; reg++) {
                int r = wr*128 + mi*16 + rg*4 + reg;   // tile row; b = r&31 (m0 % 32 == 0)
                float p = acc[mi][ni][reg] + qbuf[(r & 31) * Hdim + o];
                rs[reg] += fast_tanh(p) * vo;
            }
        }
        #pragma unroll
        for (int reg = 0; reg < 4; reg++) {
            float s = rs[reg];
            s += __shfl_xor(s, 1); s += __shfl_xor(s, 2);
            s += __shfl_xor(s, 4); s += __shfl_xor(s, 8);
            if (r15 == 0) {
                int r = wr*128 + mi*16 + rg*4 + reg;
                sred[r][wc] = s;
            }
        }
    }
    __syncthreads();
    if (tid < 256)
        spart[(size_t)nblk * Mtot + m0 + tid] = sred[tid][0] + sred[tid][1] + sred[tid][2] + sred[tid][3];
#undef STAGE_A
#undef STAGE_B
#undef LDA
#undef LDB
}

// ---------------- Kernel 3: reduce 4 partials + softmax over L (per b) ----------------
__global__ __launch_bounds__(256) void softmax_kernel(
    const float* __restrict__ spart,   // [4][Mtot], m = l*32+b
    float* __restrict__ attn)          // [B][L]
{
    int b = blockIdx.x;
    int t = threadIdx.x;
    __shared__ float rmax[4], rsum[4];
    float sv[8];
    float mx = -1e30f;
    #pragma unroll
    for (int i = 0; i < 8; i++) {
        int l = t + i * 256;
        int m = l * Bdim + b;
        float s = 0.f;
        #pragma unroll
        for (int p = 0; p < 4; p++) s += spart[(size_t)p * Mtot + m];
        sv[i] = s;
        mx = fmaxf(mx, s);
    }
    #pragma unroll
    for (int off = 1; off < 64; off <<= 1) mx = fmaxf(mx, __shfl_xor(mx, off));
    if ((t & 63) == 0) rmax[t >> 6] = mx;
    __syncthreads();
    mx = fmaxf(fmaxf(rmax[0], rmax[1]), fmaxf(rmax[2], rmax[3]));
    float sum = 0.f;
    #pragma unroll
    for (int i = 0; i < 8; i++) { sv[i] = __expf(sv[i] - mx); sum += sv[i]; }
    #pragma unroll
    for (int off = 1; off < 64; off <<= 1) sum += __shfl_xor(sum, off);
    if ((t & 63) == 0) rsum[t >> 6] = sum;
    __syncthreads();
    sum = rsum[0] + rsum[1] + rsum[2] + rsum[3];
    float inv = 1.f / sum;
    #pragma unroll
    for (int i = 0; i < 8; i++)
        attn[(size_t)b * Ldim + t + i * 256] = sv[i] * inv;
}

// ---------------- Kernel 4: context partials over L-chunks (bf16 enc) ----------------
__global__ __launch_bounds__(256) void context_part_kernel(
    const short* __restrict__ enc_bf,
    const float* __restrict__ attn,
    float* __restrict__ cpart)         // [64][B][H]
{
    int b = blockIdx.x & 31;
    int c = blockIdx.x >> 5;
    int t = threadIdx.x;
    float a0 = 0.f, a1 = 0.f, a2 = 0.f, a3 = 0.f;
    int l0 = c * 32;
    for (int i = 0; i < 32; i++) {
        int l = l0 + i;
        float a = attn[(size_t)b * Ldim + l];
        short4v e = *(const short4v*)(enc_bf + (size_t)(l * Bdim + b) * Hdim + t * 4);
        a0 += a * bf2f(e.x); a1 += a * bf2f(e.y);
        a2 += a * bf2f(e.z); a3 += a * bf2f(e.w);
    }
    float4 r; r.x = a0; r.y = a1; r.z = a2; r.w = a3;
    *(float4*)(cpart + ((size_t)c * Bdim + b) * Hdim + t * 4) = r;
}

// ---------------- Kernel 5: reduce context partials ----------------
__global__ __launch_bounds__(256) void context_reduce_kernel(
    const float* __restrict__ cpart, float* __restrict__ out)
{
    int idx = blockIdx.x * 256 + threadIdx.x;
    float s = 0.f;
    for (int c = 0; c < 64; c++) s += cpart[(size_t)c * (Bdim * Hdim) + idx];
    out[idx] = s;
}

extern "C" void kernel_launch(void* const* d_in, const int* in_sizes, int n_in,
                              void* d_out, int out_size, void* d_ws, size_t ws_size,
                              hipStream_t stream)
{
    const float* hidden = (const float*)d_in[0];
    const float* enc    = (const float*)d_in[1];   // (L,B,H), m = l*32+b
    const float* attn_w = (const float*)d_in[2];
    const float* attn_b = (const float*)d_in[3];
    const float* vvec   = (const float*)d_in[4];
    float* out = (float*)d_out;

    char* ws = (char*)d_ws;
    size_t off = 0;
    short* enc_bf = (short*)(ws + off); off += (size_t)Mtot * Hdim * 2;       // 134.2 MB
    short* w_bf   = (short*)(ws + off); off += (size_t)Hdim * Hdim * 2;       //   2.1 MB
    float* qbuf   = (float*)(ws + off); off += (size_t)Bdim * Hdim * 4;       //   0.13 MB
    float* spart  = (float*)(ws + off); off += (size_t)4 * Mtot * 4;          //   1.0 MB
    float* attnp  = (float*)(ws + off); off += (size_t)Mtot * 4;              //   0.26 MB
    float* cpart  = (float*)(ws + off);                                       //   8.4 MB

    convert_enc_kernel<<<32768, 256, 0, stream>>>(enc, enc_bf);
    convert_w_kernel<<<512, 256, 0, stream>>>(attn_w, w_bf);
    qproj_kernel<<<8192, 256, 0, stream>>>(hidden, attn_w, attn_b, qbuf);
    scores_kernel<<<1024, 512, 0, stream>>>(enc_bf, w_bf, qbuf, vvec, spart);
    softmax_kernel<<<Bdim, 256, 0, stream>>>(spart, attnp);
    context_part_kernel<<<2048, 256, 0, stream>>>(enc_bf, attnp, cpart);
    context_reduce_kernel<<<128, 256, 0, stream>>>(cpart, out);
}

// Round 9
// 283.351 us; speedup vs baseline: 1.1043x; 1.0069x over previous
//
#include <hip/hip_runtime.h>
#include <hip/hip_bf16.h>
#include <math.h>

#define Hdim 1024
#define Bdim 32
#define Ldim 2048
#define Mtot (Bdim*Ldim)   // 65536

typedef __attribute__((ext_vector_type(8))) short short8v;
typedef __attribute__((ext_vector_type(4))) short short4v;
typedef __attribute__((ext_vector_type(4))) float floatx4;

static __device__ inline short f2bf(float f) {
    union { float f; unsigned u; } x; x.f = f;
    unsigned r = x.u + 0x7FFF + ((x.u >> 16) & 1);   // RNE
    return (short)(r >> 16);
}
static __device__ inline float bf2f(short s) {
    union { unsigned u; float f; } x; x.u = ((unsigned)(unsigned short)s) << 16;
    return x.f;
}

static __device__ inline float fast_tanh(float x) {
    float t = 2.0f * x;
    t = fminf(fmaxf(t, -30.0f), 30.0f);
    float e = __expf(t);
    return (e - 1.0f) / (e + 1.0f);
}

typedef __attribute__((address_space(1))) const void GVT;
typedef __attribute__((address_space(3))) void LVT;
static __device__ inline void gload_lds16(const void* g, void* l) {
    __builtin_amdgcn_global_load_lds((GVT*)g, (LVT*)l, 16, 0, 0);
}

// ---------------- Kernel 0a: enc f32 -> bf16 ----------------
__global__ __launch_bounds__(256) void convert_enc_kernel(
    const float* __restrict__ enc, short* __restrict__ enc_bf)
{
    size_t i = ((size_t)blockIdx.x * 256 + threadIdx.x) * 8;
    float4 a = *(const float4*)(enc + i);
    float4 b = *(const float4*)(enc + i + 4);
    short8v o;
    o[0]=f2bf(a.x); o[1]=f2bf(a.y); o[2]=f2bf(a.z); o[3]=f2bf(a.w);
    o[4]=f2bf(b.x); o[5]=f2bf(b.y); o[6]=f2bf(b.z); o[7]=f2bf(b.w);
    *(short8v*)(enc_bf + i) = o;
}

// ---------------- Kernel 0b: W_e f32 -> compact bf16 [1024][1024] ----------------
__global__ __launch_bounds__(256) void convert_w_kernel(
    const float* __restrict__ attn_w, short* __restrict__ w_bf)
{
    int t = blockIdx.x * 256 + threadIdx.x;
    int o = t >> 7;
    int c = t & 127;
    const float* src = attn_w + (size_t)o * 2 * Hdim + Hdim + c * 8;
    float4 a = *(const float4*)(src);
    float4 b = *(const float4*)(src + 4);
    short8v v;
    v[0]=f2bf(a.x); v[1]=f2bf(a.y); v[2]=f2bf(a.z); v[3]=f2bf(a.w);
    v[4]=f2bf(b.x); v[5]=f2bf(b.y); v[6]=f2bf(b.z); v[7]=f2bf(b.w);
    *(short8v*)(w_bf + (size_t)o * Hdim + c * 8) = v;
}

// ---------------- Kernel 1: q[b][o] = hidden[b]·W_h[o] + bias[o] ----------------
__global__ __launch_bounds__(256) void qproj_kernel(
    const float* __restrict__ hidden, const float* __restrict__ attn_w,
    const float* __restrict__ attn_b, float* __restrict__ qbuf)
{
    int w = blockIdx.x * 4 + (threadIdx.x >> 6);
    int lane = threadIdx.x & 63;
    int o = w >> 5;
    int b = w & 31;
    const float* hrow = hidden + b * Hdim;
    const float* wrow = attn_w + (size_t)o * 2 * Hdim;
    float s = 0.f;
    #pragma unroll
    for (int i = 0; i < 16; i++) s += hrow[lane + i*64] * wrow[lane + i*64];
    s += __shfl_xor(s, 1);  s += __shfl_xor(s, 2);  s += __shfl_xor(s, 4);
    s += __shfl_xor(s, 8);  s += __shfl_xor(s, 16); s += __shfl_xor(s, 32);
    if (lane == 0) qbuf[b * Hdim + o] = s + attn_b[o];
}

// ---------------- Kernel 2: triple-buffered counted-vmcnt bf16 GEMM + tanh + v-dot ----
// BK=32, 3 LDS buffers, 2-K-tile prefetch distance, ONE barrier + ONE vmcnt(4)/tile.
// Wave strips 128x64 (low LDS traffic). Read swizzle chunk ^= (r15^(r15>>2))&3 via
// pre-swizzled global source (gload_lds dest stays linear).
#define NKT 32

__global__ __launch_bounds__(512, 1) void scores_kernel(
    const short* __restrict__ enc_bf,   // [Mtot][1024] bf16
    const short* __restrict__ w_bf,     // [1024][1024] bf16
    const float* __restrict__ qbuf,     // [B][H]
    const float* __restrict__ vvec,     // [H]
    float* __restrict__ spart)          // [4][Mtot]
{
    __shared__ short As[3][256*32];     // 3 x 16 KB
    __shared__ short Bs[3][256*32];     // 3 x 16 KB
    __shared__ float sred[256][4];      // 4 KB

    // XCD swizzle: grid 1024 = 8 XCD x (4 nblk x 32 mtile); nblk fastest
    int hw  = blockIdx.x;
    int xcd = hw & 7;
    int i7  = hw >> 3;
    int nblk  = i7 & 3;
    int mtile = xcd * 32 + (i7 >> 2);
    int m0 = mtile * 256;
    int n0 = nblk * 256;

    int tid = threadIdx.x;
    int w   = tid >> 6;                 // 0..7
    int l   = tid & 63;
    int wr  = w >> 2;                   // 0..1 (M half)
    int wc  = w & 3;                    // 0..3 (N quarter)
    int r15 = l & 15;
    int kc  = l >> 4;                   // 0..3 (16B chunk / row-group)

    // staging: each gload_lds covers 16 rows x 64B. lane l -> row l>>2, chunk l&3.
    // pre-swizzle global source so LDS chunk c holds global chunk c ^ s(row).
    int srow = l >> 2;                                  // 0..15
    int ssw  = (srow ^ (srow >> 2)) & 3;
    const int glsw = srow * Hdim + (((l & 3) ^ ssw) * 8);

#define STAGE_A(bb, k0) do { \
    const short* _g = enc_bf + (size_t)(m0 + w*16) * Hdim + (k0) + glsw; \
    gload_lds16(_g,                    &As[bb][(w*16)*32]);       \
    gload_lds16(_g + (size_t)128*Hdim, &As[bb][(w*16+128)*32]);   \
} while (0)
#define STAGE_B(bb, k0) do { \
    const short* _g = w_bf + (size_t)(n0 + w*16) * Hdim + (k0) + glsw; \
    gload_lds16(_g,                    &Bs[bb][(w*16)*32]);       \
    gload_lds16(_g + (size_t)128*Hdim, &Bs[bb][(w*16+128)*32]);   \
} while (0)

    // read swizzle: global chunk kc of row R lives at LDS chunk kc ^ s(R&15)
    int s15 = (r15 ^ (r15 >> 2)) & 3;
    int rc  = (kc ^ s15) * 8;
#define LDA(mi) (*(const short8v*)(&As[cur][(wr*128 + (mi)*16 + r15)*32 + rc]))
#define LDB(ni) (*(const short8v*)(&Bs[cur][(wc*64  + (ni)*16 + r15)*32 + rc]))

    floatx4 acc[8][4];
    #pragma unroll
    for (int i = 0; i < 8; i++)
        #pragma unroll
        for (int j = 0; j < 4; j++) acc[i][j] = (floatx4){0.f, 0.f, 0.f, 0.f};

    // prologue: stage tiles 0 and 1 (8 loads/thread outstanding)
    STAGE_A(0, 0);  STAGE_B(0, 0);
    STAGE_A(1, 32); STAGE_B(1, 32);

    int cur = 0;
    for (int t = 0; t < NKT; t++) {
        // wait for tile t's 4 loads (oldest); tile t+1's 4 stay in flight
        if (t < NKT - 1) asm volatile("s_waitcnt vmcnt(4)" ::: "memory");
        else             asm volatile("s_waitcnt vmcnt(0)" ::: "memory");
        __builtin_amdgcn_s_barrier();

        short8v af[8], bf[4];
        #pragma unroll
        for (int mi = 0; mi < 8; mi++) af[mi] = LDA(mi);
        #pragma unroll
        for (int ni = 0; ni < 4; ni++) bf[ni] = LDB(ni);

        // stage tile t+2 into the buffer tile t-1 just finished reading
        if (t + 2 < NKT) {
            int nb = cur + 2; if (nb >= 3) nb -= 3;
            STAGE_A(nb, (t + 2) * 32);
            STAGE_B(nb, (t + 2) * 32);
        }

        __builtin_amdgcn_s_setprio(1);
        #pragma unroll
        for (int mi = 0; mi < 8; mi++)
            #pragma unroll
            for (int ni = 0; ni < 4; ni++)
                acc[mi][ni] = __builtin_amdgcn_mfma_f32_16x16x32_bf16(af[mi], bf[ni], acc[mi][ni], 0, 0, 0);
        __builtin_amdgcn_s_setprio(0);

        cur++; if (cur >= 3) cur -= 3;
    }

    // ---- epilogue: tanh(proj + q) * v, reduce over the block's 256 cols ----
    #pragma unroll
    for (int mi = 0; mi < 8; mi++) {
        float rs[4] = {0.f, 0.f, 0.f, 0.f};
        #pragma unroll
        for (int ni = 0; ni < 4; ni++) {
            int o = n0 + wc*64 + ni*16 + r15;
            float vo = vvec[o];
            #pragma unroll
            for (int reg = 0; reg < 4; reg++) {
                int r = wr*128 + mi*16 + kc*4 + reg;   // tile row; b = r&31
                float p = acc[mi][ni][reg] + qbuf[(r & 31) * Hdim + o];
                rs[reg] += fast_tanh(p) * vo;
            }
        }
        #pragma unroll
        for (int reg = 0; reg < 4; reg++) {
            float s = rs[reg];
            s += __shfl_xor(s, 1); s += __shfl_xor(s, 2);
            s += __shfl_xor(s, 4); s += __shfl_xor(s, 8);
            if (r15 == 0) {
                int r = wr*128 + mi*16 + kc*4 + reg;
                sred[r][wc] = s;
            }
        }
    }
    __syncthreads();
    if (tid < 256)
        spart[(size_t)nblk * Mtot + m0 + tid] = sred[tid][0] + sred[tid][1] + sred[tid][2] + sred[tid][3];
#undef STAGE_A
#undef STAGE_B
#undef LDA
#undef LDB
}

// ---------------- Kernel 3: reduce 4 partials + softmax over L (per b) ----------------
__global__ __launch_bounds__(256) void softmax_kernel(
    const float* __restrict__ spart,   // [4][Mtot], m = l*32+b
    float* __restrict__ attn)          // [B][L]
{
    int b = blockIdx.x;
    int t = threadIdx.x;
    __shared__ float rmax[4], rsum[4];
    float sv[8];
    float mx = -1e30f;
    #pragma unroll
    for (int i = 0; i < 8; i++) {
        int l = t + i * 256;
        int m = l * Bdim + b;
        float s = 0.f;
        #pragma unroll
        for (int p = 0; p < 4; p++) s += spart[(size_t)p * Mtot + m];
        sv[i] = s;
        mx = fmaxf(mx, s);
    }
    #pragma unroll
    for (int off = 1; off < 64; off <<= 1) mx = fmaxf(mx, __shfl_xor(mx, off));
    if ((t & 63) == 0) rmax[t >> 6] = mx;
    __syncthreads();
    mx = fmaxf(fmaxf(rmax[0], rmax[1]), fmaxf(rmax[2], rmax[3]));
    float sum = 0.f;
    #pragma unroll
    for (int i = 0; i < 8; i++) { sv[i] = __expf(sv[i] - mx); sum += sv[i]; }
    #pragma unroll
    for (int off = 1; off < 64; off <<= 1) sum += __shfl_xor(sum, off);
    if ((t & 63) == 0) rsum[t >> 6] = sum;
    __syncthreads();
    sum = rsum[0] + rsum[1] + rsum[2] + rsum[3];
    float inv = 1.f / sum;
    #pragma unroll
    for (int i = 0; i < 8; i++)
        attn[(size_t)b * Ldim + t + i * 256] = sv[i] * inv;
}

// ---------------- Kernel 4: context partials over L-chunks (bf16 enc) ----------------
__global__ __launch_bounds__(256) void context_part_kernel(
    const short* __restrict__ enc_bf,
    const float* __restrict__ attn,
    float* __restrict__ cpart)         // [64][B][H]
{
    int b = blockIdx.x & 31;
    int c = blockIdx.x >> 5;
    int t = threadIdx.x;
    float a0 = 0.f, a1 = 0.f, a2 = 0.f, a3 = 0.f;
    int l0 = c * 32;
    for (int i = 0; i < 32; i++) {
        int l = l0 + i;
        float a = attn[(size_t)b * Ldim + l];
        short4v e = *(const short4v*)(enc_bf + (size_t)(l * Bdim + b) * Hdim + t * 4);
        a0 += a * bf2f(e.x); a1 += a * bf2f(e.y);
        a2 += a * bf2f(e.z); a3 += a * bf2f(e.w);
    }
    float4 r; r.x = a0; r.y = a1; r.z = a2; r.w = a3;
    *(float4*)(cpart + ((size_t)c * Bdim + b) * Hdim + t * 4) = r;
}

// ---------------- Kernel 5: reduce context partials ----------------
__global__ __launch_bounds__(256) void context_reduce_kernel(
    const float* __restrict__ cpart, float* __restrict__ out)
{
    int idx = blockIdx.x * 256 + threadIdx.x;
    float s = 0.f;
    for (int c = 0; c < 64; c++) s += cpart[(size_t)c * (Bdim * Hdim) + idx];
    out[idx] = s;
}

extern "C" void kernel_launch(void* const* d_in, const int* in_sizes, int n_in,
                              void* d_out, int out_size, void* d_ws, size_t ws_size,
                              hipStream_t stream)
{
    const float* hidden = (const float*)d_in[0];
    const float* enc    = (const float*)d_in[1];   // (L,B,H), m = l*32+b
    const float* attn_w = (const float*)d_in[2];
    const float* attn_b = (const float*)d_in[3];
    const float* vvec   = (const float*)d_in[4];
    float* out = (float*)d_out;

    char* ws = (char*)d_ws;
    size_t off = 0;
    short* enc_bf = (short*)(ws + off); off += (size_t)Mtot * Hdim * 2;       // 134.2 MB
    short* w_bf   = (short*)(ws + off); off += (size_t)Hdim * Hdim * 2;       //   2.1 MB
    float* qbuf   = (float*)(ws + off); off += (size_t)Bdim * Hdim * 4;       //   0.13 MB
    float* spart  = (float*)(ws + off); off += (size_t)4 * Mtot * 4;          //   1.0 MB
    float* attnp  = (float*)(ws + off); off += (size_t)Mtot * 4;              //   0.26 MB
    float* cpart  = (float*)(ws + off);                                       //   8.4 MB

    convert_enc_kernel<<<32768, 256, 0, stream>>>(enc, enc_bf);
    convert_w_kernel<<<512, 256, 0, stream>>>(attn_w, w_bf);
    qproj_kernel<<<8192, 256, 0, stream>>>(hidden, attn_w, attn_b, qbuf);
    scores_kernel<<<1024, 512, 0, stream>>>(enc_bf, w_bf, qbuf, vvec, spart);
    softmax_kernel<<<Bdim, 256, 0, stream>>>(spart, attnp);
    context_part_kernel<<<2048, 256, 0, stream>>>(enc_bf, attnp, cpart);
    context_reduce_kernel<<<128, 256, 0, stream>>>(cpart, out);
}